// Round 4
// baseline (1394.148 us; speedup 1.0000x reference)
//
#include <hip/hip_runtime.h>
#include <hip/hip_fp16.h>
#include <math.h>

// GCN: h1 = relu(norm_agg(x@W1) + b1); h2 = relu(norm_agg(h1@W2) + b2);
// out = sigmoid(h2@fc_w + fc_b)
// norm_agg(z)[d] = dinv[d]*( sum_{s->d} dinv[s]*z[s] + dinv[d]*z[d] )
//
// Round 4: k_agg was FETCH-bound (469MB random 64B gathers) + latency-limited
// (Occ 28%, VALUBusy 0.3%). Fix: fp16 y rows (half the bytes), 4-way edge
// unroll (4x MLP), 512-thread agg blocks (32 waves/CU).

#define SHIFT 9
#define BSZ 512              // nodes per bucket (1<<SHIFT)
#define EB 2048              // edge-chunk blocks for hist/part
#define SRCMASK 0x7FFFFu     // 19 bits: N <= 524288

static inline int idiv_up(long a, long b) { return (int)((a + b - 1) / b); }

// ---------------- partition pass ----------------
__global__ void k_hist(const int* __restrict__ dst, long E, long chunk,
                       unsigned* __restrict__ C, int NBUCK) {
    __shared__ unsigned cnt[1024];
    for (int t = threadIdx.x; t < 1024; t += 256) cnt[t] = 0u;
    __syncthreads();
    long e0 = (long)blockIdx.x * chunk;
    long e1 = e0 + chunk; if (e1 > E) e1 = E;
    for (long k = e0 + threadIdx.x; k < e1; k += 256)
        atomicAdd(&cnt[(unsigned)dst[k] >> SHIFT], 1u);
    __syncthreads();
    for (int bk = threadIdx.x; bk < NBUCK; bk += 256)
        C[(size_t)bk * EB + blockIdx.x] = cnt[bk];
}

__global__ void k_bsum(const unsigned* __restrict__ in, long L, unsigned* __restrict__ bsum) {
    __shared__ unsigned s[256];
    long base = (long)blockIdx.x * 1024 + threadIdx.x * 4;
    unsigned t = 0;
#pragma unroll
    for (int j = 0; j < 4; ++j) { long idx = base + j; if (idx < L) t += in[idx]; }
    s[threadIdx.x] = t;
    __syncthreads();
    for (int o = 128; o > 0; o >>= 1) {
        if (threadIdx.x < (unsigned)o) s[threadIdx.x] += s[threadIdx.x + o];
        __syncthreads();
    }
    if (threadIdx.x == 0) bsum[blockIdx.x] = s[0];
}

__global__ void k_scan_boff(unsigned* bsum, int NB) {
    __shared__ unsigned s[512];
    unsigned carry = 0;
    for (int base = 0; base < NB; base += 512) {
        int idx = base + threadIdx.x;
        unsigned v = (idx < NB) ? bsum[idx] : 0u;
        s[threadIdx.x] = v;
        __syncthreads();
        for (int o = 1; o < 512; o <<= 1) {
            unsigned a = (threadIdx.x >= (unsigned)o) ? s[threadIdx.x - o] : 0u;
            __syncthreads();
            s[threadIdx.x] += a;
            __syncthreads();
        }
        if (idx < NB) bsum[idx] = carry + s[threadIdx.x] - v;  // exclusive
        unsigned tot = s[511];
        __syncthreads();
        carry += tot;
    }
}

__global__ void k_scan_final(const unsigned* __restrict__ in, long L,
                             const unsigned* __restrict__ boff, unsigned* __restrict__ out) {
    __shared__ unsigned s[256];
    long base = (long)blockIdx.x * 1024 + threadIdx.x * 4;
    unsigned v[4]; unsigned t = 0;
#pragma unroll
    for (int j = 0; j < 4; ++j) { long idx = base + j; v[j] = (idx < L) ? in[idx] : 0u; t += v[j]; }
    s[threadIdx.x] = t;
    __syncthreads();
    for (int o = 1; o < 256; o <<= 1) {
        unsigned a = (threadIdx.x >= (unsigned)o) ? s[threadIdx.x - o] : 0u;
        __syncthreads();
        s[threadIdx.x] += a;
        __syncthreads();
    }
    unsigned run = s[threadIdx.x] - t + boff[blockIdx.x];
#pragma unroll
    for (int j = 0; j < 4; ++j) {
        long idx = base + j;
        if (idx < L) { out[idx] = run; run += v[j]; }
    }
}

__global__ void k_part(const int* __restrict__ src, const int* __restrict__ dst, long E,
                       long chunk, const unsigned* __restrict__ Coff,
                       unsigned* __restrict__ P, int NBUCK) {
    __shared__ unsigned cur[1024];
    for (int bk = threadIdx.x; bk < NBUCK; bk += 256)
        cur[bk] = Coff[(size_t)bk * EB + blockIdx.x];
    __syncthreads();
    long e0 = (long)blockIdx.x * chunk;
    long e1 = e0 + chunk; if (e1 > E) e1 = E;
    for (long k = e0 + threadIdx.x; k < e1; k += 256) {
        unsigned s = (unsigned)src[k], d = (unsigned)dst[k];
        unsigned bk = d >> SHIFT;
        unsigned pos = atomicAdd(&cur[bk], 1u);  // LDS atomic
        P[pos] = s | ((d & (BSZ - 1u)) << 19);
    }
}

__global__ void k_bdeg(const unsigned* __restrict__ P, const unsigned* __restrict__ Coff,
                       long E, int NBUCK, float* __restrict__ dinv, int N) {
    __shared__ unsigned cnt[BSZ];
    for (int t = threadIdx.x; t < BSZ; t += 256) cnt[t] = 0u;
    int b = blockIdx.x;
    long bs = Coff[(size_t)b * EB];
    long be = (b + 1 < NBUCK) ? (long)Coff[(size_t)(b + 1) * EB] : E;
    __syncthreads();
    for (long k = bs + threadIdx.x; k < be; k += 256)
        atomicAdd(&cnt[P[k] >> 19], 1u);
    __syncthreads();
    int base = b << SHIFT;
    for (int t = threadIdx.x; t < BSZ; t += 256) {
        int node = base + t;
        if (node < N) dinv[node] = rsqrtf((float)(cnt[t] + 1u));
    }
}

// ---------------- aggregation (fp16 y, unrolled, 512 threads) ----------------
// row load helper: C/8 uint4 per row
template <int C>
__device__ inline void loadrow(const __half* __restrict__ y, unsigned v, uint4* r) {
    unsigned s = v & SRCMASK;
    const uint4* yp = (const uint4*)(y + (size_t)s * C);
#pragma unroll
    for (int q = 0; q < C / 8; ++q) r[q] = yp[q];
}

template <int C>
__device__ inline void scatrow(float* __restrict__ sacc, unsigned v, const uint4* r) {
    unsigned dl = v >> 19;
#pragma unroll
    for (int q = 0; q < C / 8; ++q) {
        const __half2* hp = (const __half2*)&r[q];
#pragma unroll
        for (int j = 0; j < 4; ++j) {
            float2 f = __half22float2(hp[j]);
            atomicAdd(&sacc[(q * 8 + 2 * j + 0) * BSZ + dl], f.x);  // ds_add_f32
            atomicAdd(&sacc[(q * 8 + 2 * j + 1) * BSZ + dl], f.y);
        }
    }
}

template <int C>
__global__ __launch_bounds__(512) void k_agg(const unsigned* __restrict__ P,
                                             const unsigned* __restrict__ Coff, long E, int NBUCK,
                                             const __half* __restrict__ y,
                                             float* __restrict__ accG, int N) {
    __shared__ float sacc[C * BSZ];
    for (int t = threadIdx.x; t < C * BSZ; t += 512) sacc[t] = 0.f;
    int b = blockIdx.x;
    long bs = Coff[(size_t)b * EB];
    long be = (b + 1 < NBUCK) ? (long)Coff[(size_t)(b + 1) * EB] : E;
    __syncthreads();
    const long T = 512;
    long k = bs + threadIdx.x;
    for (; k + 3 * T < be; k += 4 * T) {  // 4 independent gathers in flight
        unsigned v0 = P[k], v1 = P[k + T], v2 = P[k + 2 * T], v3 = P[k + 3 * T];
        uint4 r0[C / 8], r1[C / 8], r2[C / 8], r3[C / 8];
        loadrow<C>(y, v0, r0);
        loadrow<C>(y, v1, r1);
        loadrow<C>(y, v2, r2);
        loadrow<C>(y, v3, r3);
        scatrow<C>(sacc, v0, r0);
        scatrow<C>(sacc, v1, r1);
        scatrow<C>(sacc, v2, r2);
        scatrow<C>(sacc, v3, r3);
    }
    for (; k < be; k += T) {
        unsigned v = P[k];
        uint4 r[C / 8];
        loadrow<C>(y, v, r);
        scatrow<C>(sacc, v, r);
    }
    __syncthreads();
    // writeback: one node per thread (BSZ==512==blockDim), + self-loop term
    int t = threadIdx.x;
    int node = (b << SHIFT) + t;
    if (node < N) {
        const __half* yn = y + (size_t)node * C;
        float4* op = (float4*)(accG + (size_t)node * C);
#pragma unroll
        for (int q = 0; q < C / 4; ++q) {
            float4 o;
            o.x = sacc[(4 * q + 0) * BSZ + t] + __half2float(yn[4 * q + 0]);
            o.y = sacc[(4 * q + 1) * BSZ + t] + __half2float(yn[4 * q + 1]);
            o.z = sacc[(4 * q + 2) * BSZ + t] + __half2float(yn[4 * q + 2]);
            o.w = sacc[(4 * q + 3) * BSZ + t] + __half2float(yn[4 * q + 3]);
            op[q] = o;
        }
    }
}

// ---------------- node kernels ----------------
__device__ inline uint4 pack8h(const float* o) {
    union { __half2 h2[4]; uint4 u; } z;
    z.h2[0] = __floats2half2_rn(o[0], o[1]);
    z.h2[1] = __floats2half2_rn(o[2], o[3]);
    z.h2[2] = __floats2half2_rn(o[4], o[5]);
    z.h2[3] = __floats2half2_rn(o[6], o[7]);
    return z.u;
}

// y1h[i] = fp16( (x[i]@W1)*dinv[i] )
__global__ void k_node1(const float* __restrict__ x, const float* __restrict__ W1,
                        const float* __restrict__ dinv, __half* __restrict__ y1h, int N) {
    __shared__ float sW[192];  // W1 [12][16]
    if (threadIdx.x < 192) sW[threadIdx.x] = W1[threadIdx.x];
    __syncthreads();
    int i = blockIdx.x * blockDim.x + threadIdx.x;
    if (i >= N) return;
    const float4* xp = (const float4*)(x + (size_t)i * 12);
    float4 a = xp[0], b = xp[1], c = xp[2];
    float xi[12] = {a.x, a.y, a.z, a.w, b.x, b.y, b.z, b.w, c.x, c.y, c.z, c.w};
    float di = dinv[i];
    float o[16];
#pragma unroll
    for (int cc = 0; cc < 16; ++cc) {
        float s = 0.f;
#pragma unroll
        for (int r = 0; r < 12; ++r) s = fmaf(xi[r], sW[r * 16 + cc], s);
        o[cc] = s * di;
    }
    uint4* yp = (uint4*)(y1h + (size_t)i * 16);
    yp[0] = pack8h(o);
    yp[1] = pack8h(o + 8);
}

// h1 = relu(acc1*dinv + b1); y2h = fp16( (h1@W2)*dinv )
__global__ void k_node2(const float* __restrict__ acc1, const float* __restrict__ W2,
                        const float* __restrict__ b1, const float* __restrict__ dinv,
                        __half* __restrict__ y2h, int N) {
    __shared__ float sW[128];  // W2 [16][8]
    __shared__ float sb[16];
    if (threadIdx.x < 128) sW[threadIdx.x] = W2[threadIdx.x];
    if (threadIdx.x < 16) sb[threadIdx.x] = b1[threadIdx.x];
    __syncthreads();
    int i = blockIdx.x * blockDim.x + threadIdx.x;
    if (i >= N) return;
    float di = dinv[i];
    const float4* ap = (const float4*)(acc1 + (size_t)i * 16);
    float h[16];
#pragma unroll
    for (int q = 0; q < 4; ++q) {
        float4 v = ap[q];
        h[4 * q + 0] = fmaxf(fmaf(v.x, di, sb[4 * q + 0]), 0.f);
        h[4 * q + 1] = fmaxf(fmaf(v.y, di, sb[4 * q + 1]), 0.f);
        h[4 * q + 2] = fmaxf(fmaf(v.z, di, sb[4 * q + 2]), 0.f);
        h[4 * q + 3] = fmaxf(fmaf(v.w, di, sb[4 * q + 3]), 0.f);
    }
    float o[8];
#pragma unroll
    for (int k = 0; k < 8; ++k) {
        float s = 0.f;
#pragma unroll
        for (int c = 0; c < 16; ++c) s = fmaf(h[c], sW[c * 8 + k], s);
        o[k] = s * di;
    }
    *(uint4*)(y2h + (size_t)i * 8) = pack8h(o);
}

// h2 = relu(acc2*dinv + b2); out = sigmoid(h2@fc_w + fc_b)
__global__ void k_node3(const float* __restrict__ acc2, const float* __restrict__ b2,
                        const float* __restrict__ fcw, const float* __restrict__ fcb,
                        const float* __restrict__ dinv, float* __restrict__ out, int N) {
    __shared__ float sb[8], sw[8], sfb[1];
    if (threadIdx.x < 8) {
        sb[threadIdx.x] = b2[threadIdx.x];
        sw[threadIdx.x] = fcw[threadIdx.x];
    }
    if (threadIdx.x == 0) sfb[0] = fcb[0];
    __syncthreads();
    int i = blockIdx.x * blockDim.x + threadIdx.x;
    if (i >= N) return;
    float di = dinv[i];
    const float4* ap = (const float4*)(acc2 + (size_t)i * 8);
    float s = sfb[0];
#pragma unroll
    for (int q = 0; q < 2; ++q) {
        float4 v = ap[q];
        s = fmaf(fmaxf(fmaf(v.x, di, sb[4 * q + 0]), 0.f), sw[4 * q + 0], s);
        s = fmaf(fmaxf(fmaf(v.y, di, sb[4 * q + 1]), 0.f), sw[4 * q + 1], s);
        s = fmaf(fmaxf(fmaf(v.z, di, sb[4 * q + 2]), 0.f), sw[4 * q + 2], s);
        s = fmaf(fmaxf(fmaf(v.w, di, sb[4 * q + 3]), 0.f), sw[4 * q + 3], s);
    }
    out[i] = 1.f / (1.f + expf(-s));
}

// ---------------- fallback path (f32, global atomics) ----------------
__global__ void k_deg(const int* __restrict__ dst, long E, unsigned* __restrict__ deg) {
    long i = (long)blockIdx.x * blockDim.x + threadIdx.x;
    long stride = (long)gridDim.x * blockDim.x;
    for (long e = i; e < E; e += stride)
        atomicAdd(&deg[dst[e]], 1u);
}

__global__ void k_dinv(const unsigned* __restrict__ deg, float* __restrict__ dinv, int N) {
    int i = blockIdx.x * blockDim.x + threadIdx.x;
    if (i < N) dinv[i] = rsqrtf((float)(deg[i] + 1u));
}

__global__ void k_node1f(const float* __restrict__ x, const float* __restrict__ W1,
                         const float* __restrict__ dinv, float* __restrict__ y1,
                         float* __restrict__ acc1, int N) {
    __shared__ float sW[192];
    if (threadIdx.x < 192) sW[threadIdx.x] = W1[threadIdx.x];
    __syncthreads();
    int i = blockIdx.x * blockDim.x + threadIdx.x;
    if (i >= N) return;
    const float4* xp = (const float4*)(x + (size_t)i * 12);
    float4 a = xp[0], b = xp[1], c = xp[2];
    float xi[12] = {a.x, a.y, a.z, a.w, b.x, b.y, b.z, b.w, c.x, c.y, c.z, c.w};
    float di = dinv[i];
    float o[16];
#pragma unroll
    for (int cc = 0; cc < 16; ++cc) {
        float s = 0.f;
#pragma unroll
        for (int r = 0; r < 12; ++r) s = fmaf(xi[r], sW[r * 16 + cc], s);
        o[cc] = s * di;
    }
    float4* yp = (float4*)(y1 + (size_t)i * 16);
    float4* ap = (float4*)(acc1 + (size_t)i * 16);
#pragma unroll
    for (int q = 0; q < 4; ++q) {
        float4 v = make_float4(o[4 * q], o[4 * q + 1], o[4 * q + 2], o[4 * q + 3]);
        yp[q] = v; ap[q] = v;
    }
}

__global__ void k_node2f(const float* __restrict__ acc1, const float* __restrict__ W2,
                         const float* __restrict__ b1, const float* __restrict__ dinv,
                         float* __restrict__ y2, float* __restrict__ acc2, int N) {
    __shared__ float sW[128];
    __shared__ float sb[16];
    if (threadIdx.x < 128) sW[threadIdx.x] = W2[threadIdx.x];
    if (threadIdx.x < 16) sb[threadIdx.x] = b1[threadIdx.x];
    __syncthreads();
    int i = blockIdx.x * blockDim.x + threadIdx.x;
    if (i >= N) return;
    float di = dinv[i];
    const float4* ap = (const float4*)(acc1 + (size_t)i * 16);
    float h[16];
#pragma unroll
    for (int q = 0; q < 4; ++q) {
        float4 v = ap[q];
        h[4 * q + 0] = fmaxf(fmaf(v.x, di, sb[4 * q + 0]), 0.f);
        h[4 * q + 1] = fmaxf(fmaf(v.y, di, sb[4 * q + 1]), 0.f);
        h[4 * q + 2] = fmaxf(fmaf(v.z, di, sb[4 * q + 2]), 0.f);
        h[4 * q + 3] = fmaxf(fmaf(v.w, di, sb[4 * q + 3]), 0.f);
    }
    float o[8];
#pragma unroll
    for (int k = 0; k < 8; ++k) {
        float s = 0.f;
#pragma unroll
        for (int c = 0; c < 16; ++c) s = fmaf(h[c], sW[c * 8 + k], s);
        o[k] = s * di;
    }
    float4* yp = (float4*)(y2 + (size_t)i * 8);
    float4* a2 = (float4*)(acc2 + (size_t)i * 8);
#pragma unroll
    for (int q = 0; q < 2; ++q) {
        float4 v = make_float4(o[4 * q], o[4 * q + 1], o[4 * q + 2], o[4 * q + 3]);
        yp[q] = v; a2[q] = v;
    }
}

template <int C>
__global__ void k_edge(const int* __restrict__ src, const int* __restrict__ dst, long E,
                       const float* __restrict__ y, float* __restrict__ acc) {
    long i = (long)blockIdx.x * blockDim.x + threadIdx.x;
    long stride = (long)gridDim.x * blockDim.x;
    for (long e = i; e < E; e += stride) {
        int s = src[e], d = dst[e];
        const float4* ys = (const float4*)(y + (size_t)s * C);
        float* ad = acc + (size_t)d * C;
#pragma unroll
        for (int q = 0; q < C / 4; ++q) {
            float4 v = ys[q];
            unsafeAtomicAdd(ad + 4 * q + 0, v.x);
            unsafeAtomicAdd(ad + 4 * q + 1, v.y);
            unsafeAtomicAdd(ad + 4 * q + 2, v.z);
            unsafeAtomicAdd(ad + 4 * q + 3, v.w);
        }
    }
}

extern "C" void kernel_launch(void* const* d_in, const int* in_sizes, int n_in,
                              void* d_out, int out_size, void* d_ws, size_t ws_size,
                              hipStream_t stream) {
    const float* x   = (const float*)d_in[0];
    const int*   ei  = (const int*)d_in[1];
    const float* W1  = (const float*)d_in[2];
    const float* b1  = (const float*)d_in[3];
    const float* W2  = (const float*)d_in[4];
    const float* b2  = (const float*)d_in[5];
    const float* fcw = (const float*)d_in[6];
    const float* fcb = (const float*)d_in[7];
    float* out = (float*)d_out;

    const long N = in_sizes[0] / 12;
    const long E = in_sizes[1] / 2;
    const int* src = ei;
    const int* dst = ei + E;

    const int NBUCK = idiv_up(N, BSZ);
    const long L = (long)NBUCK * EB;
    const int NB2 = idiv_up(L, 1024);
    const long chunk = (E + EB - 1) / EB;

    char* ws = (char*)d_ws;
    size_t off = 0;
    auto alloc = [&](size_t bytes) {
        void* p = ws + off;
        off += (bytes + 255) & ~(size_t)255;
        return p;
    };
    unsigned* C    = (unsigned*)alloc((size_t)L * 4);      // scanned in-place -> Coff
    unsigned* bsum = (unsigned*)alloc((size_t)NB2 * 4);
    unsigned* P    = (unsigned*)alloc((size_t)E * 4);      // packed (src | dlow<<19)
    float*    dinv = (float*)alloc((size_t)N * 4);
    __half*   y1h  = (__half*)alloc((size_t)N * 16 * 2);   // fp16 rows
    float*    acc1 = (float*)alloc((size_t)N * 16 * 4);
    __half*   y2h  = y1h;                                  // y1h dead after agg16
    float*    acc2 = acc1;                                 // acc1 dead after node2
    const bool use_new = (N <= 524288) && (off <= ws_size);

    const int B = 256;
    const int NG = idiv_up(N, B);

    if (use_new) {
        k_hist<<<EB, B, 0, stream>>>(dst, E, chunk, C, NBUCK);
        k_bsum<<<NB2, B, 0, stream>>>(C, L, bsum);
        k_scan_boff<<<1, 512, 0, stream>>>(bsum, NB2);
        k_scan_final<<<NB2, B, 0, stream>>>(C, L, bsum, C);
        k_part<<<EB, B, 0, stream>>>(src, dst, E, chunk, C, P, NBUCK);
        k_bdeg<<<NBUCK, B, 0, stream>>>(P, C, E, NBUCK, dinv, (int)N);
        k_node1<<<NG, B, 0, stream>>>(x, W1, dinv, y1h, (int)N);
        k_agg<16><<<NBUCK, 512, 0, stream>>>(P, C, E, NBUCK, y1h, acc1, (int)N);
        k_node2<<<NG, B, 0, stream>>>(acc1, W2, b1, dinv, y2h, (int)N);
        k_agg<8><<<NBUCK, 512, 0, stream>>>(P, C, E, NBUCK, y2h, acc2, (int)N);
        k_node3<<<NG, B, 0, stream>>>(acc2, b2, fcw, fcb, dinv, out, (int)N);
    } else {
        // fallback: round-1 atomic path (f32)
        size_t off2 = 0;
        auto alloc2 = [&](size_t bytes) {
            void* p = ws + off2;
            off2 += (bytes + 255) & ~(size_t)255;
            return p;
        };
        unsigned* degF  = (unsigned*)alloc2((size_t)N * 4);
        float*    dinvF = (float*)alloc2((size_t)N * 4);
        float*    y1F   = (float*)alloc2((size_t)N * 16 * 4);
        float*    acc1F = (float*)alloc2((size_t)N * 16 * 4);
        float*    y2F   = y1F;
        float*    acc2F = y1F + N * 8;
        const int EG = 2048;
        hipMemsetAsync(degF, 0, (size_t)N * 4, stream);
        k_deg<<<EG, B, 0, stream>>>(dst, E, degF);
        k_dinv<<<NG, B, 0, stream>>>(degF, dinvF, (int)N);
        k_node1f<<<NG, B, 0, stream>>>(x, W1, dinvF, y1F, acc1F, (int)N);
        k_edge<16><<<EG, B, 0, stream>>>(src, dst, E, y1F, acc1F);
        k_node2f<<<NG, B, 0, stream>>>(acc1F, W2, b1, dinvF, y2F, acc2F, (int)N);
        k_edge<8><<<EG, B, 0, stream>>>(src, dst, E, y2F, acc2F);
        k_node3<<<NG, B, 0, stream>>>(acc2F, b2, fcw, fcb, dinvF, out, (int)N);
    }
}